// Round 7
// baseline (49.424 us; speedup 1.0000x reference)
//
#include <hip/hip_runtime.h>
#include <math.h>

// DescGroupPoolandNorm (pool='shift', candidate='top1', norm='l2')
//   B=4, K=8192, CG=1024, G=8, C=128
//   s = argmax over g of desc[b,k, g]  (first channel group, first-wins)
//   out[b,k, c*8+j] = desc[b,k, c*8 + (j+s)%8] / (||desc[b,k,:]||_2 + 1e-6)
//   kpts passes through (fused, spread 256 B/block).
//
// Round-7: deeper software pipeline. RPW=8 rows/wave, prefetch distance 2:
// each wave keeps rows i (compute), i+1, i+2 (in flight) in registers ->
// 8 outstanding loads/wave while the dependent reduce->store chain of the
// current row runs. 4096 waves -> 1024 blocks = exactly 4 blocks/CU.
// VGPR ~80 (16 waves/CU): aggregate in-flight loads per CU preserved
// (16x8 vs 32x4) with half the wave turnovers.
//
// Roll math (packed layout): group of 8 floats spans an even/odd lane pair.
//   own  = lane's float4; other = __shfl_xor(own,1)
//   X = (s<4) ? own : other;  Y = the other one      // WAVE-UNIFORM select
//   result = window [s&3 .. (s&3)+3] of concat(X,Y)  // uniform switch
// (per-lane parity cancels out of the X/Y select: window start w=(s+4p)&7,
//  half h=(s>>2)^p, X=own iff p^h==0 iff s<4.)

#define ROWLEN 1024  // CG (floats per row)
#define RPW 8        // rows per wave

__device__ __forceinline__ float4 shfl_xor1(float4 v) {
    float4 r;
    r.x = __shfl_xor(v.x, 1);
    r.y = __shfl_xor(v.y, 1);
    r.z = __shfl_xor(v.z, 1);
    r.w = __shfl_xor(v.w, 1);
    return r;
}

// Window [U..U+3] of concat(X[0..3], Y[0..3]), scaled by inv.
template<int U>
__device__ __forceinline__ float4 window4(float4 X, float4 Y, float inv);
template<> __device__ __forceinline__ float4 window4<0>(float4 X, float4 Y, float inv) {
    return make_float4(X.x * inv, X.y * inv, X.z * inv, X.w * inv);
}
template<> __device__ __forceinline__ float4 window4<1>(float4 X, float4 Y, float inv) {
    return make_float4(X.y * inv, X.z * inv, X.w * inv, Y.x * inv);
}
template<> __device__ __forceinline__ float4 window4<2>(float4 X, float4 Y, float inv) {
    return make_float4(X.z * inv, X.w * inv, Y.x * inv, Y.y * inv);
}
template<> __device__ __forceinline__ float4 window4<3>(float4 X, float4 Y, float inv) {
    return make_float4(X.w * inv, Y.x * inv, Y.y * inv, Y.z * inv);
}

__device__ __forceinline__ void process_row_packed(
    const float4 v0, const float4 v1, const float4 v2, const float4 v3,
    float4* __restrict__ orow4, const int lane) {
    // ---- L2 norm (permutation-invariant): sum of squares + butterfly ----
    float ss = v0.x * v0.x + v0.y * v0.y + v0.z * v0.z + v0.w * v0.w
             + v1.x * v1.x + v1.y * v1.y + v1.z * v1.z + v1.w * v1.w
             + v2.x * v2.x + v2.y * v2.y + v2.z * v2.z + v2.w * v2.w
             + v3.x * v3.x + v3.y * v3.y + v3.z * v3.z + v3.w * v3.w;
#pragma unroll
    for (int off = 1; off < 64; off <<= 1) ss += __shfl_xor(ss, off);
    const float inv = 1.0f / (sqrtf(ss) + 1e-6f);

    // ---- argmax of row floats 0..7 (lane0: f0..3, lane1: f4..7) ----
    int bi_l = 0;
    float bv_l = v0.x;
    if (v0.y > bv_l) { bv_l = v0.y; bi_l = 1; }
    if (v0.z > bv_l) { bv_l = v0.z; bi_l = 2; }
    if (v0.w > bv_l) { bv_l = v0.w; bi_l = 3; }
    const float bv0 = __shfl(bv_l, 0);
    const float bv1 = __shfl(bv_l, 1);
    const int bi0 = __shfl(bi_l, 0);
    const int bi1 = __shfl(bi_l, 1);
    int s = (bv1 > bv0) ? (bi1 + 4) : bi0;  // first-wins: tie keeps lane0
    s = __builtin_amdgcn_readfirstlane(s);  // wave-uniform -> scalar branches

    // ---- partner halves ----
    const float4 o0 = shfl_xor1(v0);
    const float4 o1 = shfl_xor1(v1);
    const float4 o2 = shfl_xor1(v2);
    const float4 o3 = shfl_xor1(v3);

    // Wave-uniform X/Y select (parity cancels; see header comment).
    float4 X0, X1, X2, X3, Y0, Y1, Y2, Y3;
    if (s < 4) {
        X0 = v0; X1 = v1; X2 = v2; X3 = v3;
        Y0 = o0; Y1 = o1; Y2 = o2; Y3 = o3;
    } else {
        X0 = o0; X1 = o1; X2 = o2; X3 = o3;
        Y0 = v0; Y1 = v1; Y2 = v2; Y3 = v3;
    }

    float4 r0, r1, r2, r3;
    switch (s & 3) {  // uniform residual shift, compile-time indices
        case 0:
            r0 = window4<0>(X0, Y0, inv); r1 = window4<0>(X1, Y1, inv);
            r2 = window4<0>(X2, Y2, inv); r3 = window4<0>(X3, Y3, inv);
            break;
        case 1:
            r0 = window4<1>(X0, Y0, inv); r1 = window4<1>(X1, Y1, inv);
            r2 = window4<1>(X2, Y2, inv); r3 = window4<1>(X3, Y3, inv);
            break;
        case 2:
            r0 = window4<2>(X0, Y0, inv); r1 = window4<2>(X1, Y1, inv);
            r2 = window4<2>(X2, Y2, inv); r3 = window4<2>(X3, Y3, inv);
            break;
        default:
            r0 = window4<3>(X0, Y0, inv); r1 = window4<3>(X1, Y1, inv);
            r2 = window4<3>(X2, Y2, inv); r3 = window4<3>(X3, Y3, inv);
            break;
    }

    // Packed stores: 1024 B dense per instruction.
    orow4[lane] = r0;
    orow4[lane + 64] = r1;
    orow4[lane + 128] = r2;
    orow4[lane + 192] = r3;
}

__global__ __launch_bounds__(256) void REDFM_15676630630653_kernel(
    const float* __restrict__ desc, float* __restrict__ out,
    const float* __restrict__ kpts, float* __restrict__ kpts_out) {
    const int lane = threadIdx.x & 63;

    // Fold the 256 KB kpts pass-through in evenly: 256 B per block
    // (wave 0's 64 lanes). 1024 blocks x 64 floats = 65536 floats.
    if (threadIdx.x < 64) {
        const int i = blockIdx.x * 64 + threadIdx.x;
        kpts_out[i] = kpts[i];
    }

    const int wid = (blockIdx.x * 256 + threadIdx.x) >> 6;  // global wave id
    const size_t r0 = (size_t)wid * RPW;

    const float4* __restrict__ rowp = (const float4*)(desc + r0 * ROWLEN);

    // Prologue: rows r0 and r0+1 in flight (packed: 1024 B dense per instr).
    float4 c0 = rowp[lane];
    float4 c1 = rowp[lane + 64];
    float4 c2 = rowp[lane + 128];
    float4 c3 = rowp[lane + 192];
    const float4* p1 = rowp + (ROWLEN / 4);
    float4 d0 = p1[lane];
    float4 d1 = p1[lane + 64];
    float4 d2 = p1[lane + 128];
    float4 d3 = p1[lane + 192];

#pragma unroll
    for (int i = 0; i < RPW; i++) {
        float4 n0, n1, n2, n3;
        if (i + 2 < RPW) {
            // Issue row i+2's loads before consuming row i: two full rows
            // (8 dwordx4) stay in flight under the reduce + stores.
            const float4* np = rowp + (size_t)(i + 2) * (ROWLEN / 4);
            n0 = np[lane];
            n1 = np[lane + 64];
            n2 = np[lane + 128];
            n3 = np[lane + 192];
        }
        process_row_packed(c0, c1, c2, c3,
                           (float4*)(out + (r0 + i) * ROWLEN), lane);
        // Static register rotation (fully unrolled loop).
        c0 = d0; c1 = d1; c2 = d2; c3 = d3;
        if (i + 2 < RPW) { d0 = n0; d1 = n1; d2 = n2; d3 = n3; }
    }
}

extern "C" void kernel_launch(void* const* d_in, const int* in_sizes, int n_in,
                              void* d_out, int out_size, void* d_ws, size_t ws_size,
                              hipStream_t stream) {
    const float* kpts = (const float*)d_in[0];
    const float* desc = (const float*)d_in[1];
    float* out = (float*)d_out;

    const int kpts_elems = in_sizes[0];            // B*K*2 = 65536
    float* desc_out = out + kpts_elems;

    // rows = 32768 = 1024 blocks x 4 waves x RPW(8) rows. Exactly 4 blocks
    // per CU on 256 CUs -> no tail round.
    const int descBlocks = 1024;
    REDFM_15676630630653_kernel<<<descBlocks, 256, 0, stream>>>(
        desc, desc_out, kpts, out);
}

// Round 8
// 49.190 us; speedup vs baseline: 1.0048x; 1.0048x over previous
//
#include <hip/hip_runtime.h>
#include <math.h>

// DescGroupPoolandNorm (pool='shift', candidate='top1', norm='l2')
//   B=4, K=8192, CG=1024, G=8, C=128
//   s = argmax over g of desc[b,k, g]  (first channel group, first-wins)
//   out[b,k, c*8+j] = desc[b,k, c*8 + (j+s)%8] / (||desc[b,k,:]||_2 + 1e-6)
//   kpts passes through (fused, spread 128 B/block).
//
// Round-8: pair-interleaved rows. Each wave processes rows two at a time:
// 8 loads issued together, then BOTH rows' sum-of-squares butterflies and
// argmaxes run in one branch-free basic block (2x ILP through the 6-deep
// dependent shuffle chain — the only long serial section), then the two
// short uniform-branch roll+store tails. Packed float4 accesses (1024 B
// dense per instruction). 2048 blocks = 8/CU exact, 4 waves x 4 rows.
//
// Roll math (packed layout): group of 8 floats spans an even/odd lane pair.
//   own  = lane's float4; other = __shfl_xor(own,1)
//   X = (s<4) ? own : other;  Y = the other one      // WAVE-UNIFORM select
//   result = window [s&3 .. (s&3)+3] of concat(X,Y)  // uniform switch
// (per-lane parity cancels out of the X/Y select: window start w=(s+4p)&7,
//  half h=(s>>2)^p, X=own iff p^h==0 iff s<4.)

#define ROWLEN 1024  // CG (floats per row)
#define RPW 4        // rows per wave (2 pairs)

__device__ __forceinline__ float4 shfl_xor1(float4 v) {
    float4 r;
    r.x = __shfl_xor(v.x, 1);
    r.y = __shfl_xor(v.y, 1);
    r.z = __shfl_xor(v.z, 1);
    r.w = __shfl_xor(v.w, 1);
    return r;
}

// Window [U..U+3] of concat(X[0..3], Y[0..3]), scaled by inv.
template<int U>
__device__ __forceinline__ float4 window4(float4 X, float4 Y, float inv);
template<> __device__ __forceinline__ float4 window4<0>(float4 X, float4 Y, float inv) {
    return make_float4(X.x * inv, X.y * inv, X.z * inv, X.w * inv);
}
template<> __device__ __forceinline__ float4 window4<1>(float4 X, float4 Y, float inv) {
    return make_float4(X.y * inv, X.z * inv, X.w * inv, Y.x * inv);
}
template<> __device__ __forceinline__ float4 window4<2>(float4 X, float4 Y, float inv) {
    return make_float4(X.z * inv, X.w * inv, Y.x * inv, Y.y * inv);
}
template<> __device__ __forceinline__ float4 window4<3>(float4 X, float4 Y, float inv) {
    return make_float4(X.w * inv, Y.x * inv, Y.y * inv, Y.z * inv);
}

// Roll + scale + store one row given its registers, uniform shift s, inv.
__device__ __forceinline__ void roll_store(
    const float4 v0, const float4 v1, const float4 v2, const float4 v3,
    const int s, const float inv, float4* __restrict__ orow4, const int lane) {
    const float4 o0 = shfl_xor1(v0);
    const float4 o1 = shfl_xor1(v1);
    const float4 o2 = shfl_xor1(v2);
    const float4 o3 = shfl_xor1(v3);

    float4 X0, X1, X2, X3, Y0, Y1, Y2, Y3;
    if (s < 4) {
        X0 = v0; X1 = v1; X2 = v2; X3 = v3;
        Y0 = o0; Y1 = o1; Y2 = o2; Y3 = o3;
    } else {
        X0 = o0; X1 = o1; X2 = o2; X3 = o3;
        Y0 = v0; Y1 = v1; Y2 = v2; Y3 = v3;
    }

    float4 r0, r1, r2, r3;
    switch (s & 3) {
        case 0:
            r0 = window4<0>(X0, Y0, inv); r1 = window4<0>(X1, Y1, inv);
            r2 = window4<0>(X2, Y2, inv); r3 = window4<0>(X3, Y3, inv);
            break;
        case 1:
            r0 = window4<1>(X0, Y0, inv); r1 = window4<1>(X1, Y1, inv);
            r2 = window4<1>(X2, Y2, inv); r3 = window4<1>(X3, Y3, inv);
            break;
        case 2:
            r0 = window4<2>(X0, Y0, inv); r1 = window4<2>(X1, Y1, inv);
            r2 = window4<2>(X2, Y2, inv); r3 = window4<2>(X3, Y3, inv);
            break;
        default:
            r0 = window4<3>(X0, Y0, inv); r1 = window4<3>(X1, Y1, inv);
            r2 = window4<3>(X2, Y2, inv); r3 = window4<3>(X3, Y3, inv);
            break;
    }

    orow4[lane] = r0;
    orow4[lane + 64] = r1;
    orow4[lane + 128] = r2;
    orow4[lane + 192] = r3;
}

// Process TWO rows: both reduce chains interleaved in one branch-free block.
__device__ __forceinline__ void process_pair(
    const float4 a0, const float4 a1, const float4 a2, const float4 a3,
    const float4 b0, const float4 b1, const float4 b2, const float4 b3,
    float4* __restrict__ orowA, float4* __restrict__ orowB, const int lane) {
    // ---- sum of squares, both rows (independent chains -> 2x ILP) ----
    float ssa = a0.x * a0.x + a0.y * a0.y + a0.z * a0.z + a0.w * a0.w
              + a1.x * a1.x + a1.y * a1.y + a1.z * a1.z + a1.w * a1.w
              + a2.x * a2.x + a2.y * a2.y + a2.z * a2.z + a2.w * a2.w
              + a3.x * a3.x + a3.y * a3.y + a3.z * a3.z + a3.w * a3.w;
    float ssb = b0.x * b0.x + b0.y * b0.y + b0.z * b0.z + b0.w * b0.w
              + b1.x * b1.x + b1.y * b1.y + b1.z * b1.z + b1.w * b1.w
              + b2.x * b2.x + b2.y * b2.y + b2.z * b2.z + b2.w * b2.w
              + b3.x * b3.x + b3.y * b3.y + b3.z * b3.z + b3.w * b3.w;
#pragma unroll
    for (int off = 1; off < 64; off <<= 1) {
        ssa += __shfl_xor(ssa, off);
        ssb += __shfl_xor(ssb, off);
    }
    const float inva = 1.0f / (sqrtf(ssa) + 1e-6f);
    const float invb = 1.0f / (sqrtf(ssb) + 1e-6f);

    // ---- argmax of floats 0..7, both rows (lane0: f0..3, lane1: f4..7) ----
    int bia = 0;
    float bva = a0.x;
    if (a0.y > bva) { bva = a0.y; bia = 1; }
    if (a0.z > bva) { bva = a0.z; bia = 2; }
    if (a0.w > bva) { bva = a0.w; bia = 3; }
    int bib = 0;
    float bvb = b0.x;
    if (b0.y > bvb) { bvb = b0.y; bib = 1; }
    if (b0.z > bvb) { bvb = b0.z; bib = 2; }
    if (b0.w > bvb) { bvb = b0.w; bib = 3; }

    const float bva0 = __shfl(bva, 0);
    const float bva1 = __shfl(bva, 1);
    const int bia0 = __shfl(bia, 0);
    const int bia1 = __shfl(bia, 1);
    const float bvb0 = __shfl(bvb, 0);
    const float bvb1 = __shfl(bvb, 1);
    const int bib0 = __shfl(bib, 0);
    const int bib1 = __shfl(bib, 1);

    int sa = (bva1 > bva0) ? (bia1 + 4) : bia0;  // first-wins ties
    int sb = (bvb1 > bvb0) ? (bib1 + 4) : bib0;
    sa = __builtin_amdgcn_readfirstlane(sa);
    sb = __builtin_amdgcn_readfirstlane(sb);

    // ---- short branchy tails ----
    roll_store(a0, a1, a2, a3, sa, inva, orowA, lane);
    roll_store(b0, b1, b2, b3, sb, invb, orowB, lane);
}

__global__ __launch_bounds__(256) void REDFM_15676630630653_kernel(
    const float* __restrict__ desc, float* __restrict__ out,
    const float* __restrict__ kpts, float* __restrict__ kpts_out) {
    const int lane = threadIdx.x & 63;

    // kpts pass-through spread evenly: 128 B per block (first 32 lanes).
    // 2048 blocks x 32 floats = 65536 floats = 256 KB.
    if (threadIdx.x < 32) {
        const int i = blockIdx.x * 32 + threadIdx.x;
        kpts_out[i] = kpts[i];
    }

    const int wid = (blockIdx.x * 256 + threadIdx.x) >> 6;  // global wave id
    const size_t r0 = (size_t)wid * RPW;
    const float4* __restrict__ rowp = (const float4*)(desc + r0 * ROWLEN);

#pragma unroll
    for (int p = 0; p < RPW / 2; p++) {
        const float4* pa = rowp + (size_t)(2 * p) * (ROWLEN / 4);
        const float4* pb = pa + (ROWLEN / 4);
        // 8 loads issued back-to-back (all in flight together).
        const float4 a0 = pa[lane];
        const float4 a1 = pa[lane + 64];
        const float4 a2 = pa[lane + 128];
        const float4 a3 = pa[lane + 192];
        const float4 b0 = pb[lane];
        const float4 b1 = pb[lane + 64];
        const float4 b2 = pb[lane + 128];
        const float4 b3 = pb[lane + 192];

        process_pair(a0, a1, a2, a3, b0, b1, b2, b3,
                     (float4*)(out + (r0 + 2 * p) * ROWLEN),
                     (float4*)(out + (r0 + 2 * p + 1) * ROWLEN), lane);
    }
}

extern "C" void kernel_launch(void* const* d_in, const int* in_sizes, int n_in,
                              void* d_out, int out_size, void* d_ws, size_t ws_size,
                              hipStream_t stream) {
    const float* kpts = (const float*)d_in[0];
    const float* desc = (const float*)d_in[1];
    float* out = (float*)d_out;

    const int kpts_elems = in_sizes[0];            // B*K*2 = 65536
    float* desc_out = out + kpts_elems;

    // rows = 32768 = 2048 blocks x 4 waves x RPW(4) rows. 8 blocks/CU exact.
    const int descBlocks = 2048;
    REDFM_15676630630653_kernel<<<descBlocks, 256, 0, stream>>>(
        desc, desc_out, kpts, out);
}